// Round 6
// baseline (36485.422 us; speedup 1.0000x reference)
//
#include <hip/hip_runtime.h>

#define NROWS 32768
#define KC 8192
#define DDIM 256
#define D4 64
#define CAP 64
#define DELTA 4e-4f
#define MT 128
#define NSEG 8
#define SEGC (KC / NSEG)   // 1024 codes per block
#define PAN 64             // codes per panel
#define NPAN (SEGC / PAN)  // 16 panels

typedef _Float16 half8 __attribute__((ext_vector_type(8)));
typedef float f32x4 __attribute__((ext_vector_type(4)));
typedef unsigned int uint;
typedef const __attribute__((address_space(1))) unsigned int* gptr_u32;
typedef __attribute__((address_space(3))) unsigned int* lptr_u32;

union H4 { ushort4 u; _Float16 h[4]; };

// fmin-reduce over each 16-lane row via DPP row_ror (pure VALU, no LDS pipe)
template <int CTRL>
__device__ __forceinline__ float rormin_step(float x) {
  const int v = __builtin_amdgcn_mov_dpp(__float_as_int(x), CTRL, 0xf, 0xf, true);
  return fminf(x, __int_as_float(v));
}
__device__ __forceinline__ float redmin16(float x) {
  x = rormin_step<0x121>(x);  // row_ror:1
  x = rormin_step<0x122>(x);  // row_ror:2
  x = rormin_step<0x124>(x);  // row_ror:4
  x = rormin_step<0x128>(x);  // row_ror:8
  return x;
}

// ---------------- kernel 1: bit-exact numpy pairwise row norm ----------------
__global__ __launch_bounds__(64) void vq_znorm(const float* __restrict__ z,
                                               float* __restrict__ An) {
#pragma clang fp contract(off)
  const int row = blockIdx.x * 64 + threadIdx.x;
  const float4* p4 = (const float4*)(z + (size_t)row * 256);
  float halves[2];
#pragma unroll
  for (int h = 0; h < 2; ++h) {
    float r[8];
    float4 a = p4[h * 32 + 0], b = p4[h * 32 + 1];
    r[0] = a.x * a.x; r[1] = a.y * a.y; r[2] = a.z * a.z; r[3] = a.w * a.w;
    r[4] = b.x * b.x; r[5] = b.y * b.y; r[6] = b.z * b.z; r[7] = b.w * b.w;
    for (int i = 1; i < 16; ++i) {  // 8-element chunks in numpy pairwise order
      a = p4[h * 32 + i * 2];
      b = p4[h * 32 + i * 2 + 1];
      r[0] += a.x * a.x; r[1] += a.y * a.y; r[2] += a.z * a.z; r[3] += a.w * a.w;
      r[4] += b.x * b.x; r[5] += b.y * b.y; r[6] += b.z * b.z; r[7] += b.w * b.w;
    }
    halves[h] = ((r[0] + r[1]) + (r[2] + r[3])) + ((r[4] + r[5]) + (r[6] + r[7]));
  }
  An[row] = halves[0] + halves[1];
}

// ---------------- kernel 2: f32 -> f16 conversion (+ scale e by 2^13) + cnt init ----------------
__global__ __launch_bounds__(256) void vq_convert(const float* __restrict__ z,
                                                  const float* __restrict__ emb,
                                                  _Float16* __restrict__ z16,
                                                  _Float16* __restrict__ e16,
                                                  int* __restrict__ cnt) {
  const int tid = blockIdx.x * 256 + threadIdx.x;  // 524288 threads
  const float4* z4 = (const float4*)z;
  const float4* e4 = (const float4*)emb;
  ushort4* z16u = (ushort4*)z16;
  ushort4* e16u = (ushort4*)e16;
#pragma unroll
  for (int t = 0; t < 4; ++t) {
    const int i = tid + t * 524288;
    const float4 v = z4[i];
    H4 o;
    o.h[0] = (_Float16)v.x; o.h[1] = (_Float16)v.y;
    o.h[2] = (_Float16)v.z; o.h[3] = (_Float16)v.w;
    z16u[i] = o.u;
  }
  {
    const int i = tid;  // 524288 = 8192*64
    const float4 v = e4[i];
    H4 o;
    o.h[0] = (_Float16)(v.x * 8192.0f); o.h[1] = (_Float16)(v.y * 8192.0f);
    o.h[2] = (_Float16)(v.z * 8192.0f); o.h[3] = (_Float16)(v.w * 8192.0f);
    e16u[i] = o.u;
  }
  if (tid < NROWS) cnt[tid] = 0;
}

// ---------------- kernel 3: z-stationary f16 MFMA GEMM + fused local filter ----------------
// grid 2048 = 256 M-tiles(128 rows) x 8 N-segments; seg = bid&7 (XCD-affine).
// 4 waves = 2 row-halves x 2 code-halves; wave: 64 rows (af[4][8] in regs) x 32 codes.
// 16 panels of 64 codes, double-buffered LDS. No global rowmin: per-wave local
// threshold rl+DELTA; (code,score) appended; exact recheck prunes via approx-min.
__global__ __launch_bounds__(256) void vq_gemm_filter(
    const _Float16* __restrict__ z16, const _Float16* __restrict__ e16,
    const float* __restrict__ An, int* __restrict__ cnt,
    uint2* __restrict__ list) {
  __shared__ _Float16 smem[32768];  // 64KB: z-stage, then e-panel dbuf (2x32KB)
  const int bid = blockIdx.x;
  const int seg = bid & 7, mIdx = bid >> 3;
  const int brow = mIdx * MT;
  const int c0seg = seg * SEGC;
  const int tid = threadIdx.x;
  const int lane = tid & 63, w = tid >> 6;
  const int l15 = lane & 15, l4 = lane >> 4;
  const int wr = w >> 1, wc = w & 1;
  const int wrow = wr * 64;

  // ---- stage z tile (128x256 f16 = 64KB), source pre-swizzled: slotL = slotP ^ (row&31)
#pragma unroll
  for (int i = 0; i < 16; ++i) {
    const int c = tid + 256 * i;  // [0,4096) 16B chunks
    const int r = c >> 5, sl = (c & 31) ^ (r & 31);
    __builtin_amdgcn_global_load_lds(
        (gptr_u32)(z16 + (size_t)(brow + r) * DDIM + sl * 8),
        (lptr_u32)(smem + c * 8), 16, 0, 0);
  }
  __syncthreads();
  // ---- af register-resident: rows wrow + m*16 + l15, full K
  half8 af[4][8];
#pragma unroll
  for (int m = 0; m < 4; ++m) {
    const int row = wrow + m * 16 + l15;
#pragma unroll
    for (int k = 0; k < 8; ++k) {
      const int sl = (k * 4 + l4) ^ (row & 31);
      af[m][k] = *(const half8*)(smem + row * 256 + sl * 8);
    }
  }
  __syncthreads();  // all reads of z region done before panel staging overwrites

  float An_r[4][4];
#pragma unroll
  for (int m = 0; m < 4; ++m) {
    const f32x4 a4 = *(const f32x4*)(An + brow + wrow + m * 16 + l4 * 4);
#pragma unroll
    for (int r = 0; r < 4; ++r) An_r[m][r] = a4[r];
  }

  float rl[4][4];
#pragma unroll
  for (int m = 0; m < 4; ++m)
#pragma unroll
    for (int r = 0; r < 4; ++r) rl[m][r] = 3.4e38f;

  // prologue: stage panel 0 into buffer 0
#pragma unroll
  for (int i = 0; i < 8; ++i) {
    const int c = tid + 256 * i;  // [0,2048)
    const int r = c >> 5, sl = (c & 31) ^ (r & 31);
    __builtin_amdgcn_global_load_lds(
        (gptr_u32)(e16 + (size_t)(c0seg + r) * DDIM + sl * 8),
        (lptr_u32)(smem + c * 8), 16, 0, 0);
  }
  __syncthreads();

  for (int p = 0; p < NPAN; ++p) {
    const int curoff = (p & 1) << 14;  // 16384 f16 per buffer
    const int nxtoff = curoff ^ 16384;
    if (p + 1 < NPAN) {
      const int cb = c0seg + (p + 1) * PAN;
#pragma unroll
      for (int i = 0; i < 8; ++i) {
        const int c = tid + 256 * i;
        const int r = c >> 5, sl = (c & 31) ^ (r & 31);
        __builtin_amdgcn_global_load_lds(
            (gptr_u32)(e16 + (size_t)(cb + r) * DDIM + sl * 8),
            (lptr_u32)(smem + nxtoff + c * 8), 16, 0, 0);
      }
    }
    f32x4 acc[4][2] = {{{0.f}}};
#pragma unroll
    for (int k = 0; k < 8; ++k) {
      half8 bf[2];
#pragma unroll
      for (int n = 0; n < 2; ++n) {
        const int crow = wc * 32 + n * 16 + l15;
        const int sl = (k * 4 + l4) ^ (crow & 31);
        bf[n] = *(const half8*)(smem + curoff + crow * 256 + sl * 8);
      }
#pragma unroll
      for (int m = 0; m < 4; ++m)
#pragma unroll
        for (int n = 0; n < 2; ++n)
          acc[m][n] = __builtin_amdgcn_mfma_f32_16x16x32_f16(af[m][k], bf[n], acc[m][n], 0, 0, 0);
    }

    // ---- epilogue: scores, DPP row-min, local threshold, append ----
#pragma unroll
    for (int m = 0; m < 4; ++m) {
      float s0[4], s1[4], pm[4];
#pragma unroll
      for (int r = 0; r < 4; ++r) {
        s0[r] = fmaf(acc[m][0][r], -0x1p-12f, An_r[m][r]);  // A - 2p
        s1[r] = fmaf(acc[m][1][r], -0x1p-12f, An_r[m][r]);
        pm[r] = redmin16(fminf(s0[r], s1[r]));
        rl[m][r] = fminf(rl[m][r], pm[r]);
      }
#pragma unroll
      for (int n = 0; n < 2; ++n)
#pragma unroll
        for (int r = 0; r < 4; ++r) {
          const float sv = n ? s1[r] : s0[r];
          if (sv <= rl[m][r] + DELTA) {
            const int row = brow + wrow + m * 16 + l4 * 4 + r;
            const int code = c0seg + p * PAN + wc * 32 + n * 16 + l15;
            const int pos = atomicAdd(cnt + row, 1);
            if (pos < CAP)
              list[(size_t)row * CAP + pos] = make_uint2((uint)code, __float_as_uint(sv));
          }
        }
    }
    __syncthreads();  // next-panel staging landed; cur buffer reusable
  }
}

// ---------------- kernel 4: exact recheck (bit-exact np chain) + gather ----------------
__global__ __launch_bounds__(256) void vq_recheck_gather(
    const float* __restrict__ z, const float* __restrict__ emb,
    const float* __restrict__ An, const int* __restrict__ cnt,
    const uint2* __restrict__ list, float* __restrict__ out) {
  const int row = blockIdx.x * 4 + (threadIdx.x >> 6);
  const int lane = threadIdx.x & 63;
  const int nc = cnt[row];
  const float Ar = An[row];
  const float4* z4r = (const float4*)z + (size_t)row * D4;
  const float4* e4 = (const float4*)emb;
  float bs = 3.4e38f;
  int bi = 0x7fffffff;
  if (nc <= CAP) {
    // one candidate per lane (CAP == 64)
    uint code = 0x7fffffffu;
    float sc = 3.4e38f;
    if (lane < nc) {
      const uint2 ent = list[(size_t)row * CAP + lane];
      code = ent.x;
      sc = __uint_as_float(ent.y);
    }
    float mn = sc;
#pragma unroll
    for (int off = 1; off < 64; off <<= 1) mn = fminf(mn, __shfl_xor(mn, off, 64));
    // exact-eval only candidates within DELTA of the approx min (true argmin provably inside)
    if (lane < nc && sc <= mn + DELTA) {
      float p = 0.f;
      for (int d = 0; d < D4; ++d) {
        const float4 zv = z4r[d];
        const float4 ev = e4[(size_t)code * D4 + d];
        p = fmaf(zv.x, ev.x, p); p = fmaf(zv.y, ev.y, p);
        p = fmaf(zv.z, ev.z, p); p = fmaf(zv.w, ev.w, p);
      }
      bs = Ar - 2.0f * p;  // fl(A-2p), 2p exact
      bi = (int)code;
    }
  } else {  // overflow fallback: exact full scan
    for (int code = lane; code < KC; code += 64) {
      float p = 0.f;
      for (int d = 0; d < D4; ++d) {
        const float4 zv = z4r[d];
        const float4 ev = e4[(size_t)code * D4 + d];
        p = fmaf(zv.x, ev.x, p); p = fmaf(zv.y, ev.y, p);
        p = fmaf(zv.z, ev.z, p); p = fmaf(zv.w, ev.w, p);
      }
      const float s = Ar - 2.0f * p;
      if (s < bs || (s == bs && code < bi)) { bs = s; bi = code; }
    }
  }
#pragma unroll
  for (int off = 1; off < 64; off <<= 1) {
    const float os = __shfl_xor(bs, off, 64);
    const int oi = __shfl_xor(bi, off, 64);
    if (os < bs || (os == bs && oi < bi)) { bs = os; bi = oi; }
  }
  // all 64 lanes hold the winner; gather the output row
  const float4 v = e4[(size_t)bi * D4 + lane];
  ((float4*)out)[(size_t)row * D4 + lane] = v;
}

extern "C" void kernel_launch(void* const* d_in, const int* in_sizes, int n_in,
                              void* d_out, int out_size, void* d_ws, size_t ws_size,
                              hipStream_t stream) {
  const float* z = (const float*)d_in[0];    // [32768, 256] f32
  const float* emb = (const float*)d_in[1];  // [8192, 256] f32
  float* out = (float*)d_out;                // [32768, 256] f32

  char* wsb = (char*)d_ws;
  float* An = (float*)(wsb);                         // 128 KB
  int* cnt = (int*)(wsb + (128 << 10));              // 128 KB
  uint2* list = (uint2*)(wsb + (512 << 10));         // 32768*64*8B = 16 MB
  _Float16* z16 = (_Float16*)(wsb + (512 << 10) + (16 << 20));  // 16 MB
  _Float16* e16 = (_Float16*)(wsb + (512 << 10) + (32 << 20));  // 4 MB

  vq_znorm<<<NROWS / 64, 64, 0, stream>>>(z, An);
  vq_convert<<<2048, 256, 0, stream>>>(z, emb, z16, e16, cnt);
  vq_gemm_filter<<<2048, 256, 0, stream>>>(z16, e16, An, cnt, list);
  vq_recheck_gather<<<NROWS / 4, 256, 0, stream>>>(z, emb, An, cnt, list, out);
}

// Round 7
// 730.249 us; speedup vs baseline: 49.9630x; 49.9630x over previous
//
#include <hip/hip_runtime.h>

#define NROWS 32768
#define KC 8192
#define DDIM 256
#define D4 64
#define CAP 64
#define DELTA 4e-4f
#define MT 128
#define NSEG 8
#define SEGC (KC / NSEG)   // 1024 codes per block
#define PAN 64             // codes per panel
#define NPAN (SEGC / PAN)  // 16 panels

typedef _Float16 half8 __attribute__((ext_vector_type(8)));
typedef float f32x4 __attribute__((ext_vector_type(4)));
typedef unsigned int uint;
typedef const __attribute__((address_space(1))) unsigned int* gptr_u32;
typedef __attribute__((address_space(3))) unsigned int* lptr_u32;

union H4 { ushort4 u; _Float16 h[4]; };

// fmax-reduce over each 16-lane row via DPP row_ror (pure VALU, no LDS pipe)
template <int CTRL>
__device__ __forceinline__ float rormax_step(float x) {
  const int v = __builtin_amdgcn_mov_dpp(__float_as_int(x), CTRL, 0xf, 0xf, true);
  return fmaxf(x, __int_as_float(v));
}
__device__ __forceinline__ float redmax16(float x) {
  x = rormax_step<0x121>(x);  // row_ror:1
  x = rormax_step<0x122>(x);  // row_ror:2
  x = rormax_step<0x124>(x);  // row_ror:4
  x = rormax_step<0x128>(x);  // row_ror:8
  return x;
}

// ---------------- kernel 1: bit-exact numpy pairwise row norm ----------------
__global__ __launch_bounds__(64) void vq_znorm(const float* __restrict__ z,
                                               float* __restrict__ An) {
#pragma clang fp contract(off)
  const int row = blockIdx.x * 64 + threadIdx.x;
  const float4* p4 = (const float4*)(z + (size_t)row * 256);
  float halves[2];
#pragma unroll
  for (int h = 0; h < 2; ++h) {
    float r[8];
    float4 a = p4[h * 32 + 0], b = p4[h * 32 + 1];
    r[0] = a.x * a.x; r[1] = a.y * a.y; r[2] = a.z * a.z; r[3] = a.w * a.w;
    r[4] = b.x * b.x; r[5] = b.y * b.y; r[6] = b.z * b.z; r[7] = b.w * b.w;
    for (int i = 1; i < 16; ++i) {  // 8-element chunks in numpy pairwise order
      a = p4[h * 32 + i * 2];
      b = p4[h * 32 + i * 2 + 1];
      r[0] += a.x * a.x; r[1] += a.y * a.y; r[2] += a.z * a.z; r[3] += a.w * a.w;
      r[4] += b.x * b.x; r[5] += b.y * b.y; r[6] += b.z * b.z; r[7] += b.w * b.w;
    }
    halves[h] = ((r[0] + r[1]) + (r[2] + r[3])) + ((r[4] + r[5]) + (r[6] + r[7]));
  }
  An[row] = halves[0] + halves[1];
}

// ---------------- kernel 2: f32 -> f16 conversion (+ scale e by 2^13) + init ----------------
__global__ __launch_bounds__(256) void vq_convert(const float* __restrict__ z,
                                                  const float* __restrict__ emb,
                                                  _Float16* __restrict__ z16,
                                                  _Float16* __restrict__ e16,
                                                  int* __restrict__ cnt,
                                                  uint* __restrict__ rowmin) {
  const int tid = blockIdx.x * 256 + threadIdx.x;  // 524288 threads
  const float4* z4 = (const float4*)z;
  const float4* e4 = (const float4*)emb;
  ushort4* z16u = (ushort4*)z16;
  ushort4* e16u = (ushort4*)e16;
#pragma unroll
  for (int t = 0; t < 4; ++t) {
    const int i = tid + t * 524288;
    const float4 v = z4[i];
    H4 o;
    o.h[0] = (_Float16)v.x; o.h[1] = (_Float16)v.y;
    o.h[2] = (_Float16)v.z; o.h[3] = (_Float16)v.w;
    z16u[i] = o.u;
  }
  {
    const int i = tid;  // 524288 = 8192*64
    const float4 v = e4[i];
    H4 o;
    o.h[0] = (_Float16)(v.x * 8192.0f); o.h[1] = (_Float16)(v.y * 8192.0f);
    o.h[2] = (_Float16)(v.z * 8192.0f); o.h[3] = (_Float16)(v.w * 8192.0f);
    e16u[i] = o.u;
  }
  if (tid < NROWS) { cnt[tid] = 0; rowmin[tid] = 0x7F800000u; }  // +inf
}

// ---------------- kernel 3: z-stationary f16 MFMA GEMM + fused filter ----------------
// grid 2048 = 256 M-tiles(128 rows) x 8 N-segments; seg = bid&7 (XCD-affine).
// 4 waves = 2 row-halves x 2 code-halves; wave: 64 rows (af[4][8] in regs) x 32 codes.
// Threshold = min(wave-local running min, STALE global rowmin) + DELTA.
// Global rowmin updated fire-and-forget (no return-value wait).
__global__ __launch_bounds__(256) void vq_gemm_filter(
    const _Float16* __restrict__ z16, const _Float16* __restrict__ e16,
    const float* __restrict__ An, uint* __restrict__ rowmin,
    int* __restrict__ cnt, uint2* __restrict__ list) {
  __shared__ _Float16 smem[32768];  // 64KB: z-stage, then e-panel dbuf (2x32KB)
  const int bid = blockIdx.x;
  const int seg = bid & 7, mIdx = bid >> 3;
  const int brow = mIdx * MT;
  const int c0seg = seg * SEGC;
  const int tid = threadIdx.x;
  const int lane = tid & 63, w = tid >> 6;
  const int l15 = lane & 15, l4 = lane >> 4;
  const int wr = w >> 1, wc = w & 1;
  const int wrow = wr * 64;

  // ---- stage z tile (128x256 f16 = 64KB), source pre-swizzled: slotL = slotP ^ (row&31)
#pragma unroll
  for (int i = 0; i < 16; ++i) {
    const int c = tid + 256 * i;  // [0,4096) 16B chunks
    const int r = c >> 5, sl = (c & 31) ^ (r & 31);
    __builtin_amdgcn_global_load_lds(
        (gptr_u32)(z16 + (size_t)(brow + r) * DDIM + sl * 8),
        (lptr_u32)(smem + c * 8), 16, 0, 0);
  }
  __syncthreads();
  // ---- af register-resident: rows wrow + m*16 + l15, full K
  half8 af[4][8];
#pragma unroll
  for (int m = 0; m < 4; ++m) {
    const int row = wrow + m * 16 + l15;
#pragma unroll
    for (int k = 0; k < 8; ++k) {
      const int sl = (k * 4 + l4) ^ (row & 31);
      af[m][k] = *(const half8*)(smem + row * 256 + sl * 8);
    }
  }
  __syncthreads();  // all reads of z region done before panel staging overwrites

  float An_r[4][4];
#pragma unroll
  for (int m = 0; m < 4; ++m) {
    const f32x4 a4 = *(const f32x4*)(An + brow + wrow + m * 16 + l4 * 4);
#pragma unroll
    for (int r = 0; r < 4; ++r) An_r[m][r] = a4[r];
  }

  // running MAX of acc per (m,r)  (score = A - 2^-12*acc is monotone decreasing)
  float rlx[4][4];
#pragma unroll
  for (int m = 0; m < 4; ++m)
#pragma unroll
    for (int r = 0; r < 4; ++r) rlx[m][r] = -3.4e38f;

  // prologue: stage panel 0 into buffer 0
#pragma unroll
  for (int i = 0; i < 8; ++i) {
    const int c = tid + 256 * i;  // [0,2048)
    const int r = c >> 5, sl = (c & 31) ^ (r & 31);
    __builtin_amdgcn_global_load_lds(
        (gptr_u32)(e16 + (size_t)(c0seg + r) * DDIM + sl * 8),
        (lptr_u32)(smem + c * 8), 16, 0, 0);
  }
  __syncthreads();

  for (int p = 0; p < NPAN; ++p) {
    const int curoff = (p & 1) << 14;  // 16384 f16 per buffer
    const int nxtoff = curoff ^ 16384;
    // stale global row-min (plain load; hidden under the MFMA loop)
    float g[4][4];
#pragma unroll
    for (int m = 0; m < 4; ++m)
#pragma unroll
      for (int r = 0; r < 4; ++r)
        g[m][r] = __uint_as_float(rowmin[brow + wrow + m * 16 + l4 * 4 + r]);

    if (p + 1 < NPAN) {
      const int cb = c0seg + (p + 1) * PAN;
#pragma unroll
      for (int i = 0; i < 8; ++i) {
        const int c = tid + 256 * i;
        const int r = c >> 5, sl = (c & 31) ^ (r & 31);
        __builtin_amdgcn_global_load_lds(
            (gptr_u32)(e16 + (size_t)(cb + r) * DDIM + sl * 8),
            (lptr_u32)(smem + nxtoff + c * 8), 16, 0, 0);
      }
    }
    f32x4 acc[4][2] = {{{0.f}}};
#pragma unroll
    for (int k = 0; k < 8; ++k) {
      half8 bf[2];
#pragma unroll
      for (int n = 0; n < 2; ++n) {
        const int crow = wc * 32 + n * 16 + l15;
        const int sl = (k * 4 + l4) ^ (crow & 31);
        bf[n] = *(const half8*)(smem + curoff + crow * 256 + sl * 8);
      }
#pragma unroll
      for (int m = 0; m < 4; ++m)
#pragma unroll
        for (int n = 0; n < 2; ++n)
          acc[m][n] = __builtin_amdgcn_mfma_f32_16x16x32_f16(af[m][k], bf[n], acc[m][n], 0, 0, 0);
    }

    // ---- epilogue (acc-domain): DPP row-max, threshold limit, append ----
#pragma unroll
    for (int m = 0; m < 4; ++m) {
      float L[4];
#pragma unroll
      for (int r = 0; r < 4; ++r) {
        float pmax = fmaxf(acc[m][0][r], acc[m][1][r]);
        pmax = redmax16(pmax);
        const bool imp = pmax > rlx[m][r];
        rlx[m][r] = fmaxf(rlx[m][r], pmax);
        const float ls = fmaf(rlx[m][r], -0x1p-12f, An_r[m][r]);  // local best score
        const float gm = fminf(g[m][r], ls);
        if (imp && l15 == 0 && ls < g[m][r]) {  // fire-and-forget (no read-back)
          atomicMin(rowmin + (brow + wrow + m * 16 + l4 * 4 + r), __float_as_uint(ls));
        }
        L[r] = (An_r[m][r] - gm - DELTA) * 4096.0f;  // append iff acc >= L
      }
#pragma unroll
      for (int n = 0; n < 2; ++n)
#pragma unroll
        for (int r = 0; r < 4; ++r) {
          if (acc[m][n][r] >= L[r]) {
            const int row = brow + wrow + m * 16 + l4 * 4 + r;
            const int code = c0seg + p * PAN + wc * 32 + n * 16 + l15;
            const float sv = fmaf(acc[m][n][r], -0x1p-12f, An_r[m][r]);
            const int pos = atomicAdd(cnt + row, 1);
            if (pos < CAP)
              list[(size_t)row * CAP + pos] = make_uint2((uint)code, __float_as_uint(sv));
          }
        }
    }
    __syncthreads();  // next-panel staging landed; cur buffer reusable
  }
}

// ---------------- kernel 4: exact recheck (bit-exact np chain) + gather ----------------
__global__ __launch_bounds__(256) void vq_recheck_gather(
    const float* __restrict__ z, const float* __restrict__ emb,
    const float* __restrict__ An, const int* __restrict__ cnt,
    const uint2* __restrict__ list, float* __restrict__ out) {
  const int row = blockIdx.x * 4 + (threadIdx.x >> 6);
  const int lane = threadIdx.x & 63;
  const int nc = cnt[row];
  const float Ar = An[row];
  const float4* z4r = (const float4*)z + (size_t)row * D4;
  const float4* e4 = (const float4*)emb;
  float bs = 3.4e38f;
  int bi = 0x7fffffff;
  if (nc <= CAP) {
    // one candidate per lane (CAP == 64)
    uint code = 0x7fffffffu;
    float sc = 3.4e38f;
    if (lane < nc) {
      const uint2 ent = list[(size_t)row * CAP + lane];
      code = ent.x;
      sc = __uint_as_float(ent.y);
    }
    float mn = sc;
#pragma unroll
    for (int off = 1; off < 64; off <<= 1) mn = fminf(mn, __shfl_xor(mn, off, 64));
    // exact-eval only candidates within DELTA of the approx min (true argmin provably inside)
    if (lane < nc && sc <= mn + DELTA) {
      float p = 0.f;
      for (int d = 0; d < D4; ++d) {
        const float4 zv = z4r[d];
        const float4 ev = e4[(size_t)code * D4 + d];
        p = fmaf(zv.x, ev.x, p); p = fmaf(zv.y, ev.y, p);
        p = fmaf(zv.z, ev.z, p); p = fmaf(zv.w, ev.w, p);
      }
      bs = Ar - 2.0f * p;  // fl(A-2p), 2p exact
      bi = (int)code;
    }
  } else {  // overflow fallback (rare): exact full scan
    for (int code = lane; code < KC; code += 64) {
      float p = 0.f;
      for (int d = 0; d < D4; ++d) {
        const float4 zv = z4r[d];
        const float4 ev = e4[(size_t)code * D4 + d];
        p = fmaf(zv.x, ev.x, p); p = fmaf(zv.y, ev.y, p);
        p = fmaf(zv.z, ev.z, p); p = fmaf(zv.w, ev.w, p);
      }
      const float s = Ar - 2.0f * p;
      if (s < bs || (s == bs && code < bi)) { bs = s; bi = code; }
    }
  }
#pragma unroll
  for (int off = 1; off < 64; off <<= 1) {
    const float os = __shfl_xor(bs, off, 64);
    const int oi = __shfl_xor(bi, off, 64);
    if (os < bs || (os == bs && oi < bi)) { bs = os; bi = oi; }
  }
  // all 64 lanes hold the winner; gather the output row
  const float4 v = e4[(size_t)bi * D4 + lane];
  ((float4*)out)[(size_t)row * D4 + lane] = v;
}

extern "C" void kernel_launch(void* const* d_in, const int* in_sizes, int n_in,
                              void* d_out, int out_size, void* d_ws, size_t ws_size,
                              hipStream_t stream) {
  const float* z = (const float*)d_in[0];    // [32768, 256] f32
  const float* emb = (const float*)d_in[1];  // [8192, 256] f32
  float* out = (float*)d_out;                // [32768, 256] f32

  char* wsb = (char*)d_ws;
  float* An = (float*)(wsb);                         // 128 KB
  int* cnt = (int*)(wsb + (128 << 10));              // 128 KB
  uint* rowmin = (uint*)(wsb + (256 << 10));         // 128 KB
  uint2* list = (uint2*)(wsb + (512 << 10));         // 32768*64*8B = 16 MB
  _Float16* z16 = (_Float16*)(wsb + (512 << 10) + (16 << 20));  // 16 MB
  _Float16* e16 = (_Float16*)(wsb + (512 << 10) + (32 << 20));  // 4 MB

  vq_znorm<<<NROWS / 64, 64, 0, stream>>>(z, An);
  vq_convert<<<2048, 256, 0, stream>>>(z, emb, z16, e16, cnt, rowmin);
  vq_gemm_filter<<<2048, 256, 0, stream>>>(z16, e16, An, rowmin, cnt, list);
  vq_recheck_gather<<<NROWS / 4, 256, 0, stream>>>(z, emb, An, cnt, list, out);
}